// Round 5
// baseline (482.912 us; speedup 1.0000x reference)
//
#include <hip/hip_runtime.h>
#include <math.h>

#define BB 1024
#define LSx 128
#define LLx 2048
#define TOPKx 48

// ---------------------------------------------------------------------------
// Kernel 1: long-term LSH scoring, seg-tiled LDS staging + XOR slot swizzle
// + T14 async-stage split (issue seg+1 gathers before computing seg).
// Grid: (LLx/256, BB), 256 threads, 1 position per thread.
// NO forced min-occupancy bound: R4 proved __launch_bounds__(256,8) -> 32
// VGPR -> scratch spills (FETCH/WRITE +21MB each, dur +12us).
// FMA chain is bit-identical (e-ascending, seg-sequential) -> same signs ->
// same top-k -> same output.
// ---------------------------------------------------------------------------
__global__ __launch_bounds__(256) void k_score(
    const int* __restrict__ lg, const int* __restrict__ lsh, const int* __restrict__ lc,
    const int* __restrict__ ig, const int* __restrict__ ish, const int* __restrict__ ici,
    const float* __restrict__ emb, const float* __restrict__ Hm,
    signed char* __restrict__ gsc)
{
  __shared__ float Xitem[48];
  __shared__ int icode[16];
  __shared__ float4 xsh[256][4];     // one 16-float segment per row, swizzled slots
  const int b = blockIdx.y, tid = threadIdx.x;

  const int l = blockIdx.x * 256 + tid;
  const size_t off = (size_t)b * LLx + l;
  const int gid = lg[off];

  if (tid < 48) {
    const int seg = tid >> 4, e = tid & 15;
    const int id = (seg == 0) ? ig[b] : (seg == 1) ? ish[b] : ici[b];
    Xitem[tid] = emb[(size_t)id * 16 + e];
  }
  __syncthreads();
  if (tid < 16) {
    float dd = 0.f;
    for (int e = 0; e < 48; ++e) dd += Xitem[e] * Hm[e * 16 + tid];
    icode[tid] = (dd > 0.f) ? 1 : (dd < 0.f ? -1 : 0);
    // visible after the seg-0 staging barrier; read only at the end
  }

  const int srow = tid >> 2;               // stager: row within jj-tile of 64
  const int q = tid & 3;                   // stager: 16B quarter of the row
  const size_t bbase = (size_t)b * LLx + (size_t)blockIdx.x * 256;

  // ---- prologue: seg-0 gathers into registers ----
  float4 stage[4];
  #pragma unroll
  for (int jj = 0; jj < 4; ++jj) {
    const int pos = jj * 64 + srow;
    const int id = lg[bbase + pos];        // quad-broadcast, line-coalesced
    stage[jj] = *(const float4*)(emb + (size_t)id * 16 + q * 4);
  }

  float d[16];
  #pragma unroll
  for (int m = 0; m < 16; ++m) d[m] = 0.f;

  #pragma unroll
  for (int seg = 0; seg < 3; ++seg) {
    // ---- write staged registers to LDS (auto vmcnt wait on stage[]) ----
    #pragma unroll
    for (int jj = 0; jj < 4; ++jj) {
      const int pos = jj * 64 + srow;
      xsh[pos][q ^ ((pos >> 1) & 3)] = stage[jj];
    }
    __syncthreads();
    // ---- T14: issue next segment's gathers now; compute hides the latency --
    if (seg < 2) {
      const int* idn = (seg == 0) ? lsh : lc;
      #pragma unroll
      for (int jj = 0; jj < 4; ++jj) {
        const int pos = jj * 64 + srow;
        const int id = idn[bbase + pos];
        stage[jj] = *(const float4*)(emb + (size_t)id * 16 + q * 4);
      }
    }
    // ---- accumulate: bit-exact e-ascending chain ----
    if (gid != 0) {
      float x[16];
      #pragma unroll
      for (int qq = 0; qq < 4; ++qq) {
        const float4 r = xsh[tid][qq ^ ((tid >> 1) & 3)];   // conflict-free
        x[qq * 4 + 0] = r.x; x[qq * 4 + 1] = r.y;
        x[qq * 4 + 2] = r.z; x[qq * 4 + 3] = r.w;
      }
      const float* hb = Hm + seg * 256;    // H[e][m], e = seg*16+i
      #pragma unroll
      for (int i = 0; i < 16; ++i) {
        const float xi = x[i];
        #pragma unroll
        for (int mc = 0; mc < 4; ++mc) {
          const float4 h4 = *(const float4*)(hb + i * 16 + mc * 4);
          d[mc * 4 + 0] += xi * h4.x;
          d[mc * 4 + 1] += xi * h4.y;
          d[mc * 4 + 2] += xi * h4.z;
          d[mc * 4 + 3] += xi * h4.w;
        }
      }
    }
    if (seg < 2) __syncthreads();          // before next seg overwrites xsh
  }

  int sc = -1;                             // masked (reference: -inf)
  if (gid != 0) {
    sc = 0;
    #pragma unroll
    for (int m = 0; m < 16; ++m) {
      const int cs = (d[m] > 0.f) ? 1 : (d[m] < 0.f ? -1 : 0);
      sc += (cs == icode[m]) ? 1 : 0;
    }
  }
  gsc[off] = (signed char)sc;
}

// ---------------------------------------------------------------------------
// Kernel 2: short-term MHA, 256 threads, 2-way column split.
// Group w = tid>>7 owns output columns 24w..24w+23 = heads 4w..4w+3.
// Each column's kh/vh accumulation chain (e-ascending) and each head's 6-wide
// score dot live entirely in one thread -> bit-identical to the verified
// 128-thread version. Softmax/PV/output phases are byte-identical (tid<128 /
// tid<48 guards). Halves the serial projection chain, doubles wave count.
// ---------------------------------------------------------------------------
__global__ __launch_bounds__(256) void k_mha_short(
    const int* __restrict__ kg, const int* __restrict__ ks, const int* __restrict__ kc,
    const int* __restrict__ ig, const int* __restrict__ ish, const int* __restrict__ ici,
    const float* __restrict__ emb,
    const float* __restrict__ Wq, const float* __restrict__ bq,
    const float* __restrict__ Wk, const float* __restrict__ bk,
    const float* __restrict__ Wv, const float* __restrict__ bv,
    const float* __restrict__ Wo, const float* __restrict__ bo,
    float* __restrict__ outv)
{
  __shared__ float Xitem[48];
  __shared__ float qh[48];
  __shared__ __align__(16) float vhs[LSx][48];
  __shared__ float scs[8][LSx + 4];
  __shared__ float osm[48];
  __shared__ unsigned char validf[LSx];
  const int b = blockIdx.x, tid = threadIdx.x;
  const int w = tid >> 7;          // column group (0/1)
  const int k = tid & 127;         // key index

  if (tid < 48) {
    const int seg = tid >> 4, e = tid & 15;
    const int id = (seg == 0) ? ig[b] : (seg == 1) ? ish[b] : ici[b];
    Xitem[tid] = emb[(size_t)id * 16 + e];
  }
  __syncthreads();
  if (tid < 48) {
    float a = bq[tid];
    for (int e = 0; e < 48; ++e) a += Xitem[e] * Wq[e * 48 + tid];
    qh[tid] = a;
  }

  int gid, sid, cid;
  {
    const size_t off = (size_t)b * LSx + k;
    gid = kg[off]; sid = ks[off]; cid = kc[off];
  }
  // barrier (qh now visible) + count valid keys (count w==0 half only)
  const int nval = __syncthreads_count((w == 0) && (gid != 0));
  if (w == 0) validf[k] = (unsigned char)(k < nval);  // mask = position < slen

  {
    const int cb = w * 24;                 // first owned column
    float kh[24], vh[24];
    #pragma unroll
    for (int j = 0; j < 24; ++j) { kh[j] = bk[cb + j]; vh[j] = bv[cb + j]; }
    const int ids3[3] = {gid, sid, cid};
    #pragma unroll
    for (int seg = 0; seg < 3; ++seg) {
      const float* row = emb + (size_t)ids3[seg] * 16;
      #pragma unroll
      for (int i4 = 0; i4 < 4; ++i4) {
        const float4 xv = ((const float4*)row)[i4];
        const float xs[4] = {xv.x, xv.y, xv.z, xv.w};
        #pragma unroll
        for (int c = 0; c < 4; ++c) {
          const int e = seg * 16 + i4 * 4 + c;
          const float* wkr = Wk + e * 48 + cb;
          const float* wvr = Wv + e * 48 + cb;
          const float xe = xs[c];
          #pragma unroll
          for (int j = 0; j < 24; ++j) {
            kh[j] += xe * wkr[j];
            vh[j] += xe * wvr[j];
          }
        }
      }
    }
    #pragma unroll
    for (int hh = 0; hh < 4; ++hh) {
      const int h = w * 4 + hh;
      float s = 0.f;
      #pragma unroll
      for (int d = 0; d < 6; ++d) s += qh[h * 6 + d] * kh[hh * 6 + d];
      scs[h][k] = s * 0.40824829046386301637f;   // 1/sqrt(6)
    }
    #pragma unroll
    for (int j = 0; j < 24; ++j) vhs[k][cb + j] = vh[j];
  }
  __syncthreads();

  // ---- softmax: byte-identical to verified version (threads 0..127) ----
  if (tid < 128) {
    const int h = tid >> 4, l16 = tid & 15;
    float amax = -INFINITY;
    for (int kk = l16; kk < LSx; kk += 16) if (validf[kk]) amax = fmaxf(amax, scs[h][kk]);
    #pragma unroll
    for (int m = 1; m < 16; m <<= 1) amax = fmaxf(amax, __shfl_xor(amax, m, 16));
    if (nval == 0) {
      // reference: all entries get -1e9 -> fp32 rounds equal -> uniform weights
      for (int kk = l16; kk < LSx; kk += 16) scs[h][kk] = 1.0f / (float)LSx;
    } else {
      float ssum = 0.f;
      for (int kk = l16; kk < LSx; kk += 16) {
        const float ev = validf[kk] ? expf(scs[h][kk] - amax) : 0.f;
        scs[h][kk] = ev;
        ssum += ev;
      }
      #pragma unroll
      for (int m = 1; m < 16; m <<= 1) ssum += __shfl_xor(ssum, m, 16);
      const float inv = 1.0f / ssum;
      for (int kk = l16; kk < LSx; kk += 16) scs[h][kk] *= inv;
    }
  }
  __syncthreads();

  if (tid < 48) {
    const int h = tid / 6;
    float a = 0.f;
    for (int k2 = 0; k2 < LSx; ++k2) a += scs[h][k2] * vhs[k2][tid];
    osm[tid] = a;
  }
  __syncthreads();
  if (tid < 48) {
    float r = bo[tid];
    for (int j = 0; j < 48; ++j) r += osm[j] * Wo[j * 48 + tid];
    outv[b * 48 + tid] = r;
  }
}

// ---------------------------------------------------------------------------
// Kernel 3: long-term MHA with inline top-k selection (selection unchanged),
// projection phase 4-way column split: group g = tid>>6 owns columns
// 12g..12g+11 = heads 2g,2g+1; key index kk = tid&63 (active kk<48).
// Previously only 48/256 threads did the projection; now 192 do 1/4 each.
// Per-column chains and per-head dots unchanged -> bit-identical.
// ---------------------------------------------------------------------------
__global__ __launch_bounds__(256) void k_mha_long(
    const int* __restrict__ kg, const int* __restrict__ ks, const int* __restrict__ kc,
    const int* __restrict__ ig, const int* __restrict__ ish, const int* __restrict__ ici,
    const float* __restrict__ emb,
    const float* __restrict__ Wq, const float* __restrict__ bq,
    const float* __restrict__ Wk, const float* __restrict__ bk,
    const float* __restrict__ Wv, const float* __restrict__ bv,
    const float* __restrict__ Wo, const float* __restrict__ bo,
    const signed char* __restrict__ gsc,
    float* __restrict__ outv)
{
  __shared__ int hist[18];
  __shared__ int cnt_above;
  __shared__ int wsum[4];
  __shared__ int selsh[TOPKx];
  __shared__ float Xitem[48];
  __shared__ float qh[48];
  __shared__ __align__(16) float vhs[TOPKx][48];
  __shared__ float scs[8][TOPKx + 4];
  __shared__ float osm[48];
  __shared__ unsigned char validf[TOPKx];
  const int b = blockIdx.x, tid = threadIdx.x;

  // each thread owns 8 contiguous scores, kept in registers
  const int2 myv = ((const int2*)(gsc + (size_t)b * LLx))[tid];
  signed char loc[8];
  *(int2*)loc = myv;

  if (tid < 18) hist[tid] = 0;
  if (tid == 0) cnt_above = 0;
  if (tid < 48) {
    const int seg = tid >> 4, e = tid & 15;
    const int id = (seg == 0) ? ig[b] : (seg == 1) ? ish[b] : ici[b];
    Xitem[tid] = emb[(size_t)id * 16 + e];
  }
  __syncthreads();

  #pragma unroll
  for (int j = 0; j < 8; ++j) atomicAdd(&hist[(int)loc[j] + 1], 1);
  if (tid < 48) {
    float a = bq[tid];
    for (int e = 0; e < 48; ++e) a += Xitem[e] * Wq[e * 48 + tid];
    qh[tid] = a;
  }
  __syncthreads();

  // ---- threshold: all threads compute identically from the histogram ----
  int above = 0, tval = -1, need = 0;
  for (int s = 16; s >= -1; --s) {
    const int c = hist[s + 1];
    if (above + c >= TOPKx) { tval = s; need = TOPKx - above; break; }
    above += c;
  }

  // ---- tie ranking: chunked counts + block exclusive scan (ascending index) ----
  const int base_l = tid * (LLx / 256);
  int cnt = 0;
  #pragma unroll
  for (int j = 0; j < 8; ++j) cnt += ((int)loc[j] == tval) ? 1 : 0;
  int v = cnt;
  const int lane = tid & 63, wave = tid >> 6;
  #pragma unroll
  for (int o = 1; o < 64; o <<= 1) {
    const int u = __shfl_up(v, o, 64);
    if (lane >= o) v += u;
  }
  if (lane == 63) wsum[wave] = v;
  __syncthreads();
  int rank = v - cnt;
  for (int w = 0; w < wave; ++w) rank += wsum[w];

  #pragma unroll
  for (int j = 0; j < 8; ++j) {
    const int l = base_l + j;
    const int s = (int)loc[j];
    if (s > tval) {
      const int slot = atomicAdd(&cnt_above, 1);
      selsh[slot] = l;
    } else if (s == tval) {
      if (rank < need) selsh[above + rank] = l;
      ++rank;
    }
  }
  __syncthreads();

  // ---- MHA over the selected 48 positions (4-way column split) ----
  const int g = tid >> 6;          // column group (0..3)
  const int kk = tid & 63;         // key index (active < 48)
  int gid = 0, sid = 0, cid = 0;
  if (kk < TOPKx) {
    const int pos = selsh[kk];
    const size_t off = (size_t)b * LLx + pos;
    gid = kg[off]; sid = ks[off]; cid = kc[off];
  }
  const int nval = __syncthreads_count((g == 0) && (kk < TOPKx) && (gid != 0));

  if (kk < TOPKx) {
    if (g == 0) validf[kk] = (unsigned char)(gid != 0);
    const int cb = g * 12;                 // first owned column
    float kh[12], vh[12];
    #pragma unroll
    for (int j = 0; j < 12; ++j) { kh[j] = bk[cb + j]; vh[j] = bv[cb + j]; }
    const int ids3[3] = {gid, sid, cid};
    #pragma unroll
    for (int seg = 0; seg < 3; ++seg) {
      const float* row = emb + (size_t)ids3[seg] * 16;
      #pragma unroll
      for (int i4 = 0; i4 < 4; ++i4) {
        const float4 xv = ((const float4*)row)[i4];
        const float xs[4] = {xv.x, xv.y, xv.z, xv.w};
        #pragma unroll
        for (int c = 0; c < 4; ++c) {
          const int e = seg * 16 + i4 * 4 + c;
          const float* wkr = Wk + e * 48 + cb;
          const float* wvr = Wv + e * 48 + cb;
          const float xe = xs[c];
          #pragma unroll
          for (int j = 0; j < 12; ++j) {
            kh[j] += xe * wkr[j];
            vh[j] += xe * wvr[j];
          }
        }
      }
    }
    #pragma unroll
    for (int hh = 0; hh < 2; ++hh) {
      const int h = g * 2 + hh;
      float s = 0.f;
      #pragma unroll
      for (int d = 0; d < 6; ++d) s += qh[h * 6 + d] * kh[hh * 6 + d];
      scs[h][kk] = s * 0.40824829046386301637f;   // 1/sqrt(6)
    }
    #pragma unroll
    for (int j = 0; j < 12; ++j) vhs[kk][cb + j] = vh[j];
  }
  __syncthreads();

  // ---- softmax: byte-identical (threads 0..127, 16-lane groups) ----
  if (tid < 128) {
    const int h = tid >> 4, l16 = tid & 15;
    float amax = -INFINITY;
    for (int k = l16; k < TOPKx; k += 16) if (validf[k]) amax = fmaxf(amax, scs[h][k]);
    #pragma unroll
    for (int m = 1; m < 16; m <<= 1) amax = fmaxf(amax, __shfl_xor(amax, m, 16));
    if (nval == 0) {
      for (int k = l16; k < TOPKx; k += 16) scs[h][k] = 1.0f / (float)TOPKx;
    } else {
      float ssum = 0.f;
      for (int k = l16; k < TOPKx; k += 16) {
        const float ev = validf[k] ? expf(scs[h][k] - amax) : 0.f;
        scs[h][k] = ev;
        ssum += ev;
      }
      #pragma unroll
      for (int m = 1; m < 16; m <<= 1) ssum += __shfl_xor(ssum, m, 16);
      const float inv = 1.0f / ssum;
      for (int k = l16; k < TOPKx; k += 16) scs[h][k] *= inv;
    }
  }
  __syncthreads();

  if (tid < 48) {
    const int h = tid / 6;
    float a = 0.f;
    for (int k = 0; k < TOPKx; ++k) a += scs[h][k] * vhs[k][tid];
    osm[tid] = a;
  }
  __syncthreads();
  if (tid < 48) {
    float r = bo[tid];
    for (int j = 0; j < 48; ++j) r += osm[j] * Wo[j * 48 + tid];
    outv[b * 48 + tid] = r;
  }
}

// ---------------------------------------------------------------------------
// Kernel 4: MLP head (one block per batch elem) — unchanged
// ---------------------------------------------------------------------------
__device__ __forceinline__ float block_sum256(float v, float* red) {
  #pragma unroll
  for (int m = 32; m >= 1; m >>= 1) v += __shfl_xor(v, m, 64);
  const int lane = threadIdx.x & 63, wave = threadIdx.x >> 6;
  if (lane == 0) red[wave] = v;
  __syncthreads();
  const float t = red[0] + red[1] + red[2] + red[3];
  __syncthreads();
  return t;
}

__global__ __launch_bounds__(256) void k_mlp(
    const int* __restrict__ uid, const int* __restrict__ u1, const int* __restrict__ u2,
    const int* __restrict__ u3, const int* __restrict__ u4,
    const int* __restrict__ ig, const int* __restrict__ ish, const int* __restrict__ ici,
    const float* __restrict__ emb,
    const float* __restrict__ sint, const float* __restrict__ lint,
    const float* __restrict__ W1, const float* __restrict__ b1,
    const float* __restrict__ g1, const float* __restrict__ be1,
    const float* __restrict__ W2, const float* __restrict__ b2,
    const float* __restrict__ g2, const float* __restrict__ be2,
    const float* __restrict__ W3, const float* __restrict__ b3,
    float* __restrict__ out)
{
  __shared__ __align__(16) float x[224];
  __shared__ __align__(16) float h1[200];
  __shared__ float h2[80];
  __shared__ float red[4];
  const int b = blockIdx.x, tid = threadIdx.x;

  if (tid < 128) {
    const int e = tid & 15;
    int id;
    if (tid < 48) {
      const int seg = tid >> 4;
      id = (seg == 0) ? ig[b] : (seg == 1) ? ish[b] : ici[b];
    } else {
      const int f = (tid - 48) >> 4;
      id = (f == 0) ? uid[b] : (f == 1) ? u1[b] : (f == 2) ? u2[b] : (f == 3) ? u3[b] : u4[b];
    }
    x[tid] = emb[(size_t)id * 16 + e];
  } else if (tid < 176) {
    x[tid] = sint[b * 48 + (tid - 128)];
  } else if (tid < 224) {
    x[tid] = lint[b * 48 + (tid - 176)];
  }
  __syncthreads();

  float v = 0.f;
  if (tid < 200) {
    v = b1[tid];
    for (int i4 = 0; i4 < 56; ++i4) {
      const float4 xv = *(const float4*)(x + i4 * 4);
      const float* w = W1 + i4 * 4 * 200 + tid;
      v += xv.x * w[0];
      v += xv.y * w[200];
      v += xv.z * w[400];
      v += xv.w * w[600];
    }
  }
  const float mean1 = block_sum256((tid < 200) ? v : 0.f, red) * (1.0f / 200.0f);
  const float dv = (tid < 200) ? (v - mean1) : 0.f;
  const float var1 = block_sum256(dv * dv, red) * (1.0f / 200.0f);
  if (tid < 200) {
    const float y = (v - mean1) * rsqrtf(var1 + 1e-3f) * g1[tid] + be1[tid];
    h1[tid] = fmaxf(y, 0.f);
  }
  __syncthreads();

  float v2 = 0.f;
  if (tid < 80) {
    v2 = b2[tid];
    for (int i4 = 0; i4 < 50; ++i4) {
      const float4 xv = *(const float4*)(h1 + i4 * 4);
      const float* w = W2 + i4 * 4 * 80 + tid;
      v2 += xv.x * w[0];
      v2 += xv.y * w[80];
      v2 += xv.z * w[160];
      v2 += xv.w * w[240];
    }
  }
  const float mean2 = block_sum256((tid < 80) ? v2 : 0.f, red) * (1.0f / 80.0f);
  const float dv2 = (tid < 80) ? (v2 - mean2) : 0.f;
  const float var2 = block_sum256(dv2 * dv2, red) * (1.0f / 80.0f);
  if (tid < 80) {
    const float y = (v2 - mean2) * rsqrtf(var2 + 1e-3f) * g2[tid] + be2[tid];
    h2[tid] = fmaxf(y, 0.f);
  }
  __syncthreads();

  const float p = (tid < 80) ? h2[tid] * W3[tid] : 0.f;
  const float z = block_sum256(p, red);
  if (tid == 0) {
    out[b] = 1.0f / (1.0f + expf(-(z + b3[0])));
  }
}

// ---------------------------------------------------------------------------
extern "C" void kernel_launch(void* const* d_in, const int* in_sizes, int n_in,
                              void* d_out, int out_size, void* d_ws, size_t ws_size,
                              hipStream_t stream) {
  (void)in_sizes; (void)n_in; (void)out_size; (void)ws_size;
  const int* uid = (const int*)d_in[0];
  const int* u1  = (const int*)d_in[1];
  const int* u2  = (const int*)d_in[2];
  const int* u3  = (const int*)d_in[3];
  const int* u4  = (const int*)d_in[4];
  const int* ig  = (const int*)d_in[5];
  const int* ish = (const int*)d_in[6];
  const int* ici = (const int*)d_in[7];
  const int* sg  = (const int*)d_in[8];
  const int* ss  = (const int*)d_in[9];
  const int* scd = (const int*)d_in[10];
  const int* lg  = (const int*)d_in[11];
  const int* ls  = (const int*)d_in[12];
  const int* lcd = (const int*)d_in[13];
  const float* emb = (const float*)d_in[14];
  const float* Hm  = (const float*)d_in[15];
  const float* sWq = (const float*)d_in[16];
  const float* sbq = (const float*)d_in[17];
  const float* sWk = (const float*)d_in[18];
  const float* sbk = (const float*)d_in[19];
  const float* sWv = (const float*)d_in[20];
  const float* sbv = (const float*)d_in[21];
  const float* sWo = (const float*)d_in[22];
  const float* sbo = (const float*)d_in[23];
  const float* lWq = (const float*)d_in[24];
  const float* lbq = (const float*)d_in[25];
  const float* lWk = (const float*)d_in[26];
  const float* lbk = (const float*)d_in[27];
  const float* lWv = (const float*)d_in[28];
  const float* lbv = (const float*)d_in[29];
  const float* lWo = (const float*)d_in[30];
  const float* lbo = (const float*)d_in[31];
  const float* W1 = (const float*)d_in[32];
  const float* b1 = (const float*)d_in[33];
  const float* g1 = (const float*)d_in[34];
  const float* be1 = (const float*)d_in[35];
  const float* W2 = (const float*)d_in[36];
  const float* b2 = (const float*)d_in[37];
  const float* g2 = (const float*)d_in[38];
  const float* be2 = (const float*)d_in[39];
  const float* W3 = (const float*)d_in[40];
  const float* b3 = (const float*)d_in[41];
  float* out = (float*)d_out;

  // workspace layout: [scores i8: BB*LLx = 2 MB][sint: BB*48 f32][lint: BB*48 f32]
  signed char* gsc = (signed char*)d_ws;
  float* sint = (float*)((char*)d_ws + (size_t)BB * LLx);
  float* lint = sint + BB * 48;

  k_score<<<dim3(LLx / 256, BB), dim3(256), 0, stream>>>(
      lg, ls, lcd, ig, ish, ici, emb, Hm, gsc);
  k_mha_short<<<dim3(BB), dim3(256), 0, stream>>>(
      sg, ss, scd, ig, ish, ici, emb,
      sWq, sbq, sWk, sbk, sWv, sbv, sWo, sbo, sint);
  k_mha_long<<<dim3(BB), dim3(256), 0, stream>>>(
      lg, ls, lcd, ig, ish, ici, emb,
      lWq, lbq, lWk, lbk, lWv, lbv, lWo, lbo, gsc, lint);
  k_mlp<<<dim3(BB), dim3(256), 0, stream>>>(
      uid, u1, u2, u3, u4, ig, ish, ici, emb,
      sint, lint, W1, b1, g1, be1, W2, b2, g2, be2, W3, b3, out);
}

// Round 6
// 327.887 us; speedup vs baseline: 1.4728x; 1.4728x over previous
//
#include <hip/hip_runtime.h>
#include <math.h>

#define BB 1024
#define LSx 128
#define LLx 2048
#define TOPKx 48

// ---------------------------------------------------------------------------
// Kernel 1: long-term LSH scoring, seg-tiled LDS staging, padded-row layout.
// Grid: (LLx/256, BB), 256 threads, 1 position per thread. Per segment:
// quad-cooperative stage (4 lanes fetch the 4 16B-quarters of one 64B emb
// row -> coalesced), rows padded to 5 float4 (20-word stride): 20*l mod 32
// walks all 8 bank-quad groups -> BOTH ds_write_b128 and ds_read_b128 sit at
// the 8-words/bank floor (R4's XOR swizzle left 1.57M write-side conflicts).
// __launch_bounds__(256,2): VGPR cap 128 -> allocator headroom, NO spills
// (R4 forced 32 VGPR -> 21MB spills; R5's reg-staging spilled 388MB).
// FMA chain bit-identical (e-ascending, seg-sequential) -> same signs ->
// same top-k -> same output.
// ---------------------------------------------------------------------------
__global__ __launch_bounds__(256, 2) void k_score(
    const int* __restrict__ lg, const int* __restrict__ lsh, const int* __restrict__ lc,
    const int* __restrict__ ig, const int* __restrict__ ish, const int* __restrict__ ici,
    const float* __restrict__ emb, const float* __restrict__ Hm,
    signed char* __restrict__ gsc)
{
  __shared__ float Xitem[48];
  __shared__ int icode[16];
  __shared__ __align__(16) float4 xsh[256][5];   // slot 4 = pad -> 20-word stride
  const int b = blockIdx.y, tid = threadIdx.x;

  const int l = blockIdx.x * 256 + tid;
  const size_t off = (size_t)b * LLx + l;
  const int gid = lg[off];

  if (tid < 48) {
    const int seg = tid >> 4, e = tid & 15;
    const int id = (seg == 0) ? ig[b] : (seg == 1) ? ish[b] : ici[b];
    Xitem[tid] = emb[(size_t)id * 16 + e];
  }
  __syncthreads();
  if (tid < 16) {
    float dd = 0.f;
    for (int e = 0; e < 48; ++e) dd += Xitem[e] * Hm[e * 16 + tid];
    icode[tid] = (dd > 0.f) ? 1 : (dd < 0.f ? -1 : 0);
    // visible after the seg-0 staging barrier; read only at the end
  }

  const int srow = tid >> 2;               // stager: row within jj-tile of 64
  const int q = tid & 3;                   // stager: 16B quarter of the row
  const size_t bbase = (size_t)b * LLx + (size_t)blockIdx.x * 256;

  float d[16];
  #pragma unroll
  for (int m = 0; m < 16; ++m) d[m] = 0.f;

  #pragma unroll
  for (int seg = 0; seg < 3; ++seg) {
    const int* idarr = (seg == 0) ? lg : (seg == 1) ? lsh : lc;
    // ---- stage this segment's 256 rows (64B coalesced per quad) ----
    #pragma unroll
    for (int jj = 0; jj < 4; ++jj) {
      const int pos = jj * 64 + srow;
      const int id = idarr[bbase + pos];   // quad-broadcast, line-coalesced
      xsh[pos][q] = *(const float4*)(emb + (size_t)id * 16 + q * 4);
    }
    __syncthreads();
    // ---- accumulate: bit-exact e-ascending chain ----
    if (gid != 0) {
      float x[16];
      #pragma unroll
      for (int qq = 0; qq < 4; ++qq) {
        const float4 r = xsh[tid][qq];     // 20-word stride: conflict-floor
        x[qq * 4 + 0] = r.x; x[qq * 4 + 1] = r.y;
        x[qq * 4 + 2] = r.z; x[qq * 4 + 3] = r.w;
      }
      const float* hb = Hm + seg * 256;    // H[e][m], e = seg*16+i
      #pragma unroll
      for (int i = 0; i < 16; ++i) {
        const float xi = x[i];
        #pragma unroll
        for (int mc = 0; mc < 4; ++mc) {
          const float4 h4 = *(const float4*)(hb + i * 16 + mc * 4);
          d[mc * 4 + 0] += xi * h4.x;
          d[mc * 4 + 1] += xi * h4.y;
          d[mc * 4 + 2] += xi * h4.z;
          d[mc * 4 + 3] += xi * h4.w;
        }
      }
    }
    if (seg < 2) __syncthreads();          // before next seg overwrites xsh
  }

  int sc = -1;                             // masked (reference: -inf)
  if (gid != 0) {
    sc = 0;
    #pragma unroll
    for (int m = 0; m < 16; ++m) {
      const int cs = (d[m] > 0.f) ? 1 : (d[m] < 0.f ? -1 : 0);
      sc += (cs == icode[m]) ? 1 : 0;
    }
  }
  gsc[off] = (signed char)sc;
}

// ---------------------------------------------------------------------------
// Kernel 2: top-k selection (verbatim verified histogram/threshold/rank-scan
// from the R2 inline version, writing sel to global). One block per batch.
// ---------------------------------------------------------------------------
__global__ __launch_bounds__(256) void k_topk(
    const signed char* __restrict__ gsc, int* __restrict__ sel)
{
  __shared__ int hist[18];
  __shared__ int cnt_above;
  __shared__ int wsum[4];
  const int b = blockIdx.x, tid = threadIdx.x;

  // each thread owns 8 contiguous scores, kept in registers
  const int2 myv = ((const int2*)(gsc + (size_t)b * LLx))[tid];
  signed char loc[8];
  *(int2*)loc = myv;

  if (tid < 18) hist[tid] = 0;
  if (tid == 0) cnt_above = 0;
  __syncthreads();

  #pragma unroll
  for (int j = 0; j < 8; ++j) atomicAdd(&hist[(int)loc[j] + 1], 1);
  __syncthreads();

  // ---- threshold: all threads compute identically from the histogram ----
  int above = 0, tval = -1, need = 0;
  for (int s = 16; s >= -1; --s) {
    const int c = hist[s + 1];
    if (above + c >= TOPKx) { tval = s; need = TOPKx - above; break; }
    above += c;
  }

  // ---- tie ranking: chunked counts + block exclusive scan (ascending index) ----
  const int base_l = tid * (LLx / 256);
  int cnt = 0;
  #pragma unroll
  for (int j = 0; j < 8; ++j) cnt += ((int)loc[j] == tval) ? 1 : 0;
  int v = cnt;
  const int lane = tid & 63, wave = tid >> 6;
  #pragma unroll
  for (int o = 1; o < 64; o <<= 1) {
    const int u = __shfl_up(v, o, 64);
    if (lane >= o) v += u;
  }
  if (lane == 63) wsum[wave] = v;
  __syncthreads();
  int rank = v - cnt;
  for (int w = 0; w < wave; ++w) rank += wsum[w];

  #pragma unroll
  for (int j = 0; j < 8; ++j) {
    const int l = base_l + j;
    const int s = (int)loc[j];
    if (s > tval) {
      const int slot = atomicAdd(&cnt_above, 1);
      sel[b * TOPKx + slot] = l;
    } else if (s == tval) {
      if (rank < need) sel[b * TOPKx + above + rank] = l;
      ++rank;
    }
  }
}

// ---------------------------------------------------------------------------
// Kernel 3: MHA (verbatim verified 128-thread template; short K=128, long
// K=48 over selected positions). R5's column-split variants regressed the
// non-score pipeline 259 -> 306 us; reverted.
// ---------------------------------------------------------------------------
template<int K, int STRIDE, bool IS_LONG>
__global__ __launch_bounds__(128) void k_mha(
    const int* __restrict__ kg, const int* __restrict__ ks, const int* __restrict__ kc,
    const int* __restrict__ ig, const int* __restrict__ ish, const int* __restrict__ ici,
    const float* __restrict__ emb,
    const float* __restrict__ Wq, const float* __restrict__ bq,
    const float* __restrict__ Wk, const float* __restrict__ bk,
    const float* __restrict__ Wv, const float* __restrict__ bv,
    const float* __restrict__ Wo, const float* __restrict__ bo,
    const int* __restrict__ sel,
    float* __restrict__ outv)
{
  __shared__ float Xitem[48];
  __shared__ float qh[48];
  __shared__ __align__(16) float vhs[K][48];
  __shared__ float scs[8][K + 4];   // +4 pad: kill 8-way bank conflict on o-accum
  __shared__ float osm[48];
  __shared__ unsigned char validf[K];
  const int b = blockIdx.x, tid = threadIdx.x;

  if (tid < 48) {
    const int seg = tid >> 4, e = tid & 15;
    const int id = (seg == 0) ? ig[b] : (seg == 1) ? ish[b] : ici[b];
    Xitem[tid] = emb[(size_t)id * 16 + e];
  }
  __syncthreads();
  if (tid < 48) {
    float a = bq[tid];
    for (int e = 0; e < 48; ++e) a += Xitem[e] * Wq[e * 48 + tid];
    qh[tid] = a;
  }

  int gid = 0, sid = 0, cid = 0;
  if (tid < K) {
    const int pos = IS_LONG ? sel[b * TOPKx + tid] : tid;
    const size_t off = (size_t)b * STRIDE + pos;
    gid = kg[off]; sid = ks[off]; cid = kc[off];
  }
  // barrier (qh now visible) + count valid
  const int nval = __syncthreads_count((tid < K) && (gid != 0));

  if (tid < K) {
    // short: mask is position < slen; long: mask is gid != 0 on selected
    validf[tid] = IS_LONG ? (unsigned char)(gid != 0) : (unsigned char)(tid < nval);
    float kh[48], vh[48];
    #pragma unroll
    for (int j = 0; j < 48; ++j) { kh[j] = bk[j]; vh[j] = bv[j]; }
    const int ids3[3] = {gid, sid, cid};
    #pragma unroll
    for (int seg = 0; seg < 3; ++seg) {
      const float* row = emb + (size_t)ids3[seg] * 16;
      #pragma unroll
      for (int i4 = 0; i4 < 4; ++i4) {
        const float4 xv = ((const float4*)row)[i4];
        const float xs[4] = {xv.x, xv.y, xv.z, xv.w};
        #pragma unroll
        for (int c = 0; c < 4; ++c) {
          const int e = seg * 16 + i4 * 4 + c;     // uniform -> scalar loads of W rows
          const float* wkr = Wk + e * 48;
          const float* wvr = Wv + e * 48;
          const float xe = xs[c];
          #pragma unroll
          for (int j = 0; j < 48; ++j) {
            kh[j] += xe * wkr[j];
            vh[j] += xe * wvr[j];
          }
        }
      }
    }
    #pragma unroll
    for (int h = 0; h < 8; ++h) {
      float s = 0.f;
      #pragma unroll
      for (int d = 0; d < 6; ++d) s += qh[h * 6 + d] * kh[h * 6 + d];
      scs[h][tid] = s * 0.40824829046386301637f;   // 1/sqrt(6)
    }
    #pragma unroll
    for (int j = 0; j < 48; ++j) vhs[tid][j] = vh[j];
  }
  __syncthreads();

  // ---- softmax: 8 groups of 16 lanes, one head each ----
  {
    const int h = tid >> 4, l16 = tid & 15;
    float amax = -INFINITY;
    for (int k = l16; k < K; k += 16) if (validf[k]) amax = fmaxf(amax, scs[h][k]);
    #pragma unroll
    for (int m = 1; m < 16; m <<= 1) amax = fmaxf(amax, __shfl_xor(amax, m, 16));
    if (nval == 0) {
      // reference: all entries get -1e9 -> fp32 rounds equal -> uniform weights
      for (int k = l16; k < K; k += 16) scs[h][k] = 1.0f / (float)K;
    } else {
      float ssum = 0.f;
      for (int k = l16; k < K; k += 16) {
        const float ev = validf[k] ? expf(scs[h][k] - amax) : 0.f;
        scs[h][k] = ev;
        ssum += ev;
      }
      #pragma unroll
      for (int m = 1; m < 16; m <<= 1) ssum += __shfl_xor(ssum, m, 16);
      const float inv = 1.0f / ssum;
      for (int k = l16; k < K; k += 16) scs[h][k] *= inv;
    }
  }
  __syncthreads();

  if (tid < 48) {
    const int h = tid / 6;
    float a = 0.f;
    for (int k = 0; k < K; ++k) a += scs[h][k] * vhs[k][tid];
    osm[tid] = a;
  }
  __syncthreads();
  if (tid < 48) {
    float r = bo[tid];
    for (int j = 0; j < 48; ++j) r += osm[j] * Wo[j * 48 + tid];
    outv[b * 48 + tid] = r;
  }
}

// ---------------------------------------------------------------------------
// Kernel 4: MLP head (one block per batch elem) — unchanged
// ---------------------------------------------------------------------------
__device__ __forceinline__ float block_sum256(float v, float* red) {
  #pragma unroll
  for (int m = 32; m >= 1; m >>= 1) v += __shfl_xor(v, m, 64);
  const int lane = threadIdx.x & 63, wave = threadIdx.x >> 6;
  if (lane == 0) red[wave] = v;
  __syncthreads();
  const float t = red[0] + red[1] + red[2] + red[3];
  __syncthreads();
  return t;
}

__global__ __launch_bounds__(256) void k_mlp(
    const int* __restrict__ uid, const int* __restrict__ u1, const int* __restrict__ u2,
    const int* __restrict__ u3, const int* __restrict__ u4,
    const int* __restrict__ ig, const int* __restrict__ ish, const int* __restrict__ ici,
    const float* __restrict__ emb,
    const float* __restrict__ sint, const float* __restrict__ lint,
    const float* __restrict__ W1, const float* __restrict__ b1,
    const float* __restrict__ g1, const float* __restrict__ be1,
    const float* __restrict__ W2, const float* __restrict__ b2,
    const float* __restrict__ g2, const float* __restrict__ be2,
    const float* __restrict__ W3, const float* __restrict__ b3,
    float* __restrict__ out)
{
  __shared__ __align__(16) float x[224];
  __shared__ __align__(16) float h1[200];
  __shared__ float h2[80];
  __shared__ float red[4];
  const int b = blockIdx.x, tid = threadIdx.x;

  if (tid < 128) {
    const int e = tid & 15;
    int id;
    if (tid < 48) {
      const int seg = tid >> 4;
      id = (seg == 0) ? ig[b] : (seg == 1) ? ish[b] : ici[b];
    } else {
      const int f = (tid - 48) >> 4;
      id = (f == 0) ? uid[b] : (f == 1) ? u1[b] : (f == 2) ? u2[b] : (f == 3) ? u3[b] : u4[b];
    }
    x[tid] = emb[(size_t)id * 16 + e];
  } else if (tid < 176) {
    x[tid] = sint[b * 48 + (tid - 128)];
  } else if (tid < 224) {
    x[tid] = lint[b * 48 + (tid - 176)];
  }
  __syncthreads();

  float v = 0.f;
  if (tid < 200) {
    v = b1[tid];
    for (int i4 = 0; i4 < 56; ++i4) {
      const float4 xv = *(const float4*)(x + i4 * 4);
      const float* w = W1 + i4 * 4 * 200 + tid;
      v += xv.x * w[0];
      v += xv.y * w[200];
      v += xv.z * w[400];
      v += xv.w * w[600];
    }
  }
  const float mean1 = block_sum256((tid < 200) ? v : 0.f, red) * (1.0f / 200.0f);
  const float dv = (tid < 200) ? (v - mean1) : 0.f;
  const float var1 = block_sum256(dv * dv, red) * (1.0f / 200.0f);
  if (tid < 200) {
    const float y = (v - mean1) * rsqrtf(var1 + 1e-3f) * g1[tid] + be1[tid];
    h1[tid] = fmaxf(y, 0.f);
  }
  __syncthreads();

  float v2 = 0.f;
  if (tid < 80) {
    v2 = b2[tid];
    for (int i4 = 0; i4 < 50; ++i4) {
      const float4 xv = *(const float4*)(h1 + i4 * 4);
      const float* w = W2 + i4 * 4 * 80 + tid;
      v2 += xv.x * w[0];
      v2 += xv.y * w[80];
      v2 += xv.z * w[160];
      v2 += xv.w * w[240];
    }
  }
  const float mean2 = block_sum256((tid < 80) ? v2 : 0.f, red) * (1.0f / 80.0f);
  const float dv2 = (tid < 80) ? (v2 - mean2) : 0.f;
  const float var2 = block_sum256(dv2 * dv2, red) * (1.0f / 80.0f);
  if (tid < 80) {
    const float y = (v2 - mean2) * rsqrtf(var2 + 1e-3f) * g2[tid] + be2[tid];
    h2[tid] = fmaxf(y, 0.f);
  }
  __syncthreads();

  const float p = (tid < 80) ? h2[tid] * W3[tid] : 0.f;
  const float z = block_sum256(p, red);
  if (tid == 0) {
    out[b] = 1.0f / (1.0f + expf(-(z + b3[0])));
  }
}

// ---------------------------------------------------------------------------
extern "C" void kernel_launch(void* const* d_in, const int* in_sizes, int n_in,
                              void* d_out, int out_size, void* d_ws, size_t ws_size,
                              hipStream_t stream) {
  (void)in_sizes; (void)n_in; (void)out_size; (void)ws_size;
  const int* uid = (const int*)d_in[0];
  const int* u1  = (const int*)d_in[1];
  const int* u2  = (const int*)d_in[2];
  const int* u3  = (const int*)d_in[3];
  const int* u4  = (const int*)d_in[4];
  const int* ig  = (const int*)d_in[5];
  const int* ish = (const int*)d_in[6];
  const int* ici = (const int*)d_in[7];
  const int* sg  = (const int*)d_in[8];
  const int* ss  = (const int*)d_in[9];
  const int* scd = (const int*)d_in[10];
  const int* lg  = (const int*)d_in[11];
  const int* ls  = (const int*)d_in[12];
  const int* lcd = (const int*)d_in[13];
  const float* emb = (const float*)d_in[14];
  const float* Hm  = (const float*)d_in[15];
  const float* sWq = (const float*)d_in[16];
  const float* sbq = (const float*)d_in[17];
  const float* sWk = (const float*)d_in[18];
  const float* sbk = (const float*)d_in[19];
  const float* sWv = (const float*)d_in[20];
  const float* sbv = (const float*)d_in[21];
  const float* sWo = (const float*)d_in[22];
  const float* sbo = (const float*)d_in[23];
  const float* lWq = (const float*)d_in[24];
  const float* lbq = (const float*)d_in[25];
  const float* lWk = (const float*)d_in[26];
  const float* lbk = (const float*)d_in[27];
  const float* lWv = (const float*)d_in[28];
  const float* lbv = (const float*)d_in[29];
  const float* lWo = (const float*)d_in[30];
  const float* lbo = (const float*)d_in[31];
  const float* W1 = (const float*)d_in[32];
  const float* b1 = (const float*)d_in[33];
  const float* g1 = (const float*)d_in[34];
  const float* be1 = (const float*)d_in[35];
  const float* W2 = (const float*)d_in[36];
  const float* b2 = (const float*)d_in[37];
  const float* g2 = (const float*)d_in[38];
  const float* be2 = (const float*)d_in[39];
  const float* W3 = (const float*)d_in[40];
  const float* b3 = (const float*)d_in[41];
  float* out = (float*)d_out;

  // workspace: [gsc i8: BB*LLx = 2MB][sel: BB*48 int][sint: BB*48 f32][lint: BB*48 f32]
  signed char* gsc = (signed char*)d_ws;
  int* sel = (int*)((char*)d_ws + (size_t)BB * LLx);
  float* sint = (float*)(sel + BB * TOPKx);
  float* lint = sint + BB * 48;

  k_score<<<dim3(LLx / 256, BB), dim3(256), 0, stream>>>(
      lg, ls, lcd, ig, ish, ici, emb, Hm, gsc);
  k_topk<<<dim3(BB), dim3(256), 0, stream>>>(gsc, sel);
  k_mha<128, 128, false><<<dim3(BB), dim3(128), 0, stream>>>(
      sg, ss, scd, ig, ish, ici, emb,
      sWq, sbq, sWk, sbk, sWv, sbv, sWo, sbo, (const int*)nullptr, sint);
  k_mha<48, 2048, true><<<dim3(BB), dim3(128), 0, stream>>>(
      lg, ls, lcd, ig, ish, ici, emb,
      lWq, lbq, lWk, lbk, lWv, lbv, lWo, lbo, sel, lint);
  k_mlp<<<dim3(BB), dim3(256), 0, stream>>>(
      uid, u1, u2, u3, u4, ig, ish, ici, emb,
      sint, lint, W1, b1, g1, be1, W2, b2, g2, be2, W3, b3, out);
}